// Round 8
// baseline (344.625 us; speedup 1.0000x reference)
//
#include <hip/hip_runtime.h>
#include <hip/hip_bf16.h>
#include <stdint.h>

#define S_LEN 2048
#define HID   2048
#define NH    32
#define NKV   8
#define HD    64

typedef __attribute__((ext_vector_type(8))) short bf16x8;
typedef __attribute__((ext_vector_type(4))) float f32x4;
typedef __attribute__((ext_vector_type(16))) float f32x16;

__device__ __forceinline__ short f2bf(float f) {
  __hip_bfloat16 h = __float2bfloat16(f);
  return __builtin_bit_cast(short, h);
}
__device__ __forceinline__ float bf2f(short s) {
  unsigned u = ((unsigned)(unsigned short)s) << 16;
  return __builtin_bit_cast(float, u);
}
__device__ __forceinline__ int cvt_pk_bf16(float lo, float hi) {
  int r;
  asm("v_cvt_pk_bf16_f32 %0, %1, %2" : "=v"(r) : "v"(lo), "v"(hi));
  return r;
}

// ---------------- cast fp32 -> bf16 ----------------
__global__ void cast_bf16_kernel(const float* __restrict__ in, short* __restrict__ out, int n4) {
  int i = blockIdx.x * blockDim.x + threadIdx.x;
  if (i < n4) {
    float4 v = reinterpret_cast<const float4*>(in)[i];
    short4 o;
    o.x = f2bf(v.x); o.y = f2bf(v.y); o.z = f2bf(v.z); o.w = f2bf(v.w);
    reinterpret_cast<short4*>(out)[i] = o;
  }
}

// ---------------- transpose + cast: in [K][N] f32 -> out [N][K] bf16 ----------------
__global__ void transpose_cast_kernel(const float* __restrict__ in, short* __restrict__ out,
                                      int K, int N) {
  __shared__ float tile[64][65];
  const int k0 = blockIdx.x * 64;
  const int n0 = blockIdx.y * 64;
  const int tn = threadIdx.x & 63;
  const int t4 = threadIdx.x >> 6;
#pragma unroll
  for (int i = 0; i < 16; i++)
    tile[t4 + i * 4][tn] = in[(size_t)(k0 + t4 + i * 4) * N + n0 + tn];
  __syncthreads();
#pragma unroll
  for (int i = 0; i < 16; i++)
    out[(size_t)(n0 + t4 + i * 4) * K + k0 + tn] = f2bf(tile[tn][t4 + i * 4]);
}

// ---------------- concat bias [2048|512|512] ----------------
__global__ void concat_bias_kernel(const float* __restrict__ bq, const float* __restrict__ bk,
                                   const float* __restrict__ bv, float* __restrict__ out) {
  int i = blockIdx.x * blockDim.x + threadIdx.x;
  if (i < 3072) {
    float v = (i < 2048) ? bq[i] : (i < 2560 ? bk[i - 2048] : bv[i - 2560]);
    out[i] = v;
  }
}

// ---------------- RoPE tables: [S][32] cos and sin ----------------
__global__ void rope_table_kernel(float* __restrict__ ctab, float* __restrict__ stab) {
  int i = blockIdx.x * blockDim.x + threadIdx.x;
  if (i < S_LEN * 32) {
    int t = i >> 5, j = i & 31;
    float ang = (float)t * powf(10000.0f, -(float)j / 32.0f);
    ctab[i] = cosf(ang);
    stab[i] = sinf(ang);
  }
}

// ---------------- GEMM v2: C[M][N] = A[M][K] * Bt[N][K]^T + bias ----------------
template <int F32OUT>
__global__ __launch_bounds__(256, 3) void gemm_v2_kernel(
    const short* __restrict__ A, const short* __restrict__ Bt,
    const float* __restrict__ bias, void* __restrict__ Cv,
    int N, int K) {
  __shared__ short Als[2][64 * 64];
  __shared__ short Bls[2][128 * 64];
  const int tid = threadIdx.x;
  const int l = tid & 63, w = tid >> 6;
  const int lg = l >> 4, lc = l & 15;
  const int wr = w >> 1, wc = w & 1;

  const int nwg = gridDim.x;
  const int cpx = nwg >> 3;
  const int swz = (blockIdx.x & 7) * cpx + (blockIdx.x >> 3);
  const int m0 = (swz & 31) << 6;
  const int n0 = (swz >> 5) << 7;

  const int NT = K >> 6;
  const f32x4 zero4 = {0.f, 0.f, 0.f, 0.f};
  f32x4 acc[2][4];
#pragma unroll
  for (int i = 0; i < 2; i++)
#pragma unroll
    for (int j = 0; j < 4; j++) acc[i][j] = zero4;

  const int lrow = l >> 3;
  const int lcol = (l & 7) << 3;

  auto stage = [&](int buf, int kt) {
    const int kofs = kt << 6;
#pragma unroll
    for (int i = 0; i < 2; i++) {
      const short* gsrc = A + (size_t)(m0 + i * 32 + (w << 3) + lrow) * K + kofs + lcol;
      __builtin_amdgcn_global_load_lds(
          (const __attribute__((address_space(1))) unsigned*)gsrc,
          (__attribute__((address_space(3))) unsigned*)(&Als[buf][(i * 32 + (w << 3)) << 6]),
          16, 0, 0);
    }
#pragma unroll
    for (int i = 0; i < 4; i++) {
      const short* gsrc = Bt + (size_t)(n0 + i * 32 + (w << 3) + lrow) * K + kofs + lcol;
      __builtin_amdgcn_global_load_lds(
          (const __attribute__((address_space(1))) unsigned*)gsrc,
          (__attribute__((address_space(3))) unsigned*)(&Bls[buf][(i * 32 + (w << 3)) << 6]),
          16, 0, 0);
    }
  };

  stage(0, 0);
  int cur = 0;
  for (int kt = 0; kt < NT; kt++) {
    __syncthreads();
    if (kt + 1 < NT) stage(cur ^ 1, kt + 1);
    const char* AB = reinterpret_cast<const char*>(Als[cur]);
    const char* BB = reinterpret_cast<const char*>(Bls[cur]);
#pragma unroll
    for (int ks = 0; ks < 2; ks++) {
      bf16x8 af[2], bfr[4];
#pragma unroll
      for (int mi = 0; mi < 2; mi++)
        af[mi] = *reinterpret_cast<const bf16x8*>(
            AB + (wr * 32 + mi * 16 + lc) * 128 + ks * 64 + lg * 16);
#pragma unroll
      for (int nf = 0; nf < 4; nf++)
        bfr[nf] = *reinterpret_cast<const bf16x8*>(
            BB + (wc * 64 + nf * 16 + lc) * 128 + ks * 64 + lg * 16);
#pragma unroll
      for (int mi = 0; mi < 2; mi++)
#pragma unroll
        for (int nf = 0; nf < 4; nf++)
          acc[mi][nf] = __builtin_amdgcn_mfma_f32_16x16x32_bf16(af[mi], bfr[nf], acc[mi][nf], 0, 0, 0);
    }
    cur ^= 1;
  }

#pragma unroll
  for (int mi = 0; mi < 2; mi++) {
#pragma unroll
    for (int nf = 0; nf < 4; nf++) {
      int col = n0 + wc * 64 + nf * 16 + lc;
      float bv = bias[col];
#pragma unroll
      for (int r = 0; r < 4; r++) {
        int rowg = m0 + wr * 32 + mi * 16 + lg * 4 + r;
        float v = acc[mi][nf][r] + bv;
        if (F32OUT)
          reinterpret_cast<float*>(Cv)[(size_t)rowg * N + col] = v;
        else
          reinterpret_cast<short*>(Cv)[(size_t)rowg * N + col] = f2bf(v);
      }
    }
  }
}

// ---------------- fused per-head LayerNorm + RoPE ----------------
__global__ void ln_rope_kernel(const short* __restrict__ In, int instride, int nh_shift,
                               const float* __restrict__ gam, const float* __restrict__ bet,
                               const float* __restrict__ ctab, const float* __restrict__ stab,
                               float scale, short* __restrict__ Out) {
  const int lane = threadIdx.x & 63;
  const int nh = 1 << nh_shift;
  const int nrows = S_LEN << nh_shift;
  int row = (blockIdx.x * blockDim.x + threadIdx.x) >> 6;
  const int step = (gridDim.x * blockDim.x) >> 6;
  const float g = gam[lane], b = bet[lane];
  for (; row < nrows; row += step) {
    const int t = row >> nh_shift;
    const int h = row & (nh - 1);
    float x = bf2f(In[(size_t)t * instride + h * HD + lane]);
    float s = x;
#pragma unroll
    for (int m = 32; m >= 1; m >>= 1) s += __shfl_xor(s, m);
    const float mu = s * (1.0f / 64.0f);
    float d = x - mu;
    float v2 = d * d;
#pragma unroll
    for (int m = 32; m >= 1; m >>= 1) v2 += __shfl_xor(v2, m);
    const float var = v2 * (1.0f / 64.0f);
    float y = d * rsqrtf(var + 1e-5f) * g + b;
    float part = __shfl_xor(y, 32);
    const float c = ctab[t * 32 + (lane & 31)];
    const float sn = stab[t * 32 + (lane & 31)];
    float o = (lane < 32) ? (y * c - part * sn) : (y * c + part * sn);
    Out[((size_t)h * S_LEN + t) * HD + lane] = f2bf(o * scale);
  }
}

// ---------------- V transpose via LDS: [t][3072 stride] -> [g][d][t] ----------------
__global__ void v_transpose_kernel(const short* __restrict__ In, short* __restrict__ Vt) {
  __shared__ short tile[64][66];
  const int g = blockIdx.x;
  const int t0 = blockIdx.y * 64;
  const int lane = threadIdx.x & 63, w = threadIdx.x >> 6;
#pragma unroll
  for (int i = 0; i < 16; i++) {
    int r = i * 4 + w;
    tile[r][lane] = In[(size_t)(t0 + r) * 3072 + g * 64 + lane];
  }
  __syncthreads();
#pragma unroll
  for (int i = 0; i < 16; i++) {
    int d = i * 4 + w;
    Vt[((size_t)g * 64 + d) * 2048 + t0 + lane] = tile[lane][d];
  }
}

// ---------------- flash attention v3: 4 warps x 64 q each, fixed-max softmax ----------------
// Q: [NH][S][64] bf16 pre-scaled by 0.125*log2(e); K: [NKV][S][64]; Vt: [NKV][64][S]
// AO: [S][HID] bf16. Grid 256 x 256 thr. Each warp: two 32-q column blocks (qq=2).
// Fixed softmax max: |score*log2e| <= 64*0.125*1.4427 = 11.54 (LN rows have norm 8,
// RoPE preserves norm, Cauchy-Schwarz) -> p = exp2(s - 12) never overflows; softmax
// with constant max is exact (uniform scale cancels in O/l).
__global__ __launch_bounds__(256, 2) void attn_kernel(
    const short* __restrict__ Q, const short* __restrict__ Kk,
    const short* __restrict__ Vt, short* __restrict__ AO) {
  __shared__ short Kls[64 * 64];
  __shared__ short Vls[64 * 64];
  const int tid = threadIdx.x;
  const int l = tid & 63;
  const int w = tid >> 6;          // warp 0..3
  const int q31 = l & 31;
  const int h = l >> 5;            // lane half

  // XCD-aware decode: all 32 blocks on one XCD share one KV group.
  const int v = (blockIdx.x & 7) * 32 + (blockIdx.x >> 3);
  const int g = v >> 5;                       // kv group 0..7
  const int within = v & 31;
  const int head = (g << 2) + (within >> 3);  // 4 heads per group
  const int q0 = (within & 7) * 256 + w * 64; // warp covers q0..q0+63

  // Q B-frags for both q-blocks: lane -> Q[q0+qb*32+q31][ks*16 + h*8 + j]
  bf16x8 qf[2][4];
#pragma unroll
  for (int qb = 0; qb < 2; qb++) {
    const short* qbp = Q + ((size_t)head * S_LEN + q0 + qb * 32 + q31) * HD;
#pragma unroll
    for (int ks = 0; ks < 4; ks++)
      qf[qb][ks] = *reinterpret_cast<const bf16x8*>(qbp + ks * 16 + h * 8);
  }

  f32x16 oacc[2][2];
#pragma unroll
  for (int qb = 0; qb < 2; qb++)
#pragma unroll
    for (int df = 0; df < 2; df++)
#pragma unroll
      for (int r = 0; r < 16; r++) oacc[qb][df][r] = 0.f;
  float l_run[2] = {0.f, 0.f};

  // staging: 256 threads, 2 passes per tensor (64 rows x 128B)
  const int srow = tid >> 3;           // 0..31
  const int kb = (tid & 7) << 4;
  const int kbs = kb ^ ((srow & 7) << 4);
  int4 kr[2], vr[2];
  auto stage_load = [&](int kt) {
#pragma unroll
    for (int c = 0; c < 2; c++) {
      int row = c * 32 + srow;
      kr[c] = *reinterpret_cast<const int4*>(Kk + ((size_t)g * S_LEN + kt * 64 + row) * HD + (kb >> 1));
      vr[c] = *reinterpret_cast<const int4*>(Vt + ((size_t)g * HD + row) * S_LEN + kt * 64 + (kb >> 1));
    }
  };
  stage_load(0);

  const int swz = (l & 7) << 4;
  const char* KB = reinterpret_cast<const char*>(Kls);
  const char* VB = reinterpret_cast<const char*>(Vls);

  for (int kt = 0; kt < S_LEN / 64; kt++) {
    __syncthreads();  // prev tile LDS reads done
#pragma unroll
    for (int c = 0; c < 2; c++) {
      int row = c * 32 + srow;
      *reinterpret_cast<int4*>(reinterpret_cast<char*>(Kls) + row * 128 + kbs) = kr[c];
      *reinterpret_cast<int4*>(reinterpret_cast<char*>(Vls) + row * 128 + kbs) = vr[c];
    }
    if (kt + 1 < S_LEN / 64) stage_load(kt + 1);
    __syncthreads();  // staged

    // QK^T swapped, both q-blocks share each kf read: C[k][q], q = lane&31
    f32x16 sc0[2], sc1[2];
#pragma unroll
    for (int i = 0; i < 16; i++) { sc0[0][i] = 0.f; sc0[1][i] = 0.f; sc1[0][i] = 0.f; sc1[1][i] = 0.f; }
    __builtin_amdgcn_s_setprio(1);
#pragma unroll
    for (int ks = 0; ks < 4; ks++) {
#pragma unroll
      for (int kc = 0; kc < 2; kc++) {
        int row = kc * 32 + q31;
        bf16x8 kf = *reinterpret_cast<const bf16x8*>(KB + row * 128 + ((ks * 32 + h * 16) ^ swz));
        sc0[kc] = __builtin_amdgcn_mfma_f32_32x32x16_bf16(kf, qf[0][ks], sc0[kc], 0, 0, 0);
        sc1[kc] = __builtin_amdgcn_mfma_f32_32x32x16_bf16(kf, qf[1][ks], sc1[kc], 0, 0, 0);
      }
    }
    __builtin_amdgcn_s_setprio(0);

    // fixed-max softmax (log2 domain): p = exp2(s - 12), no max tracking, no rescale
    bf16x8 pa[2][4];
#pragma unroll
    for (int qb = 0; qb < 2; qb++) {
      f32x16* sc = (qb == 0) ? sc0 : sc1;
      float ps = 0.f;
#pragma unroll
      for (int kc = 0; kc < 2; kc++)
#pragma unroll
        for (int r = 0; r < 16; r++) {
          float p = __builtin_exp2f(sc[kc][r] - 12.0f);
          sc[kc][r] = p;
          ps += p;
        }
      ps += __shfl_xor(ps, 32);             // cross-half sum
      l_run[qb] += ps;

      // P(f32, C-layout) -> bf16 A/B-frags via cvt_pk + permlane32_swap (T12)
#pragma unroll
      for (int c = 0; c < 4; c++) {
        const int b0 = (c & 1) * 8;
        int wa = cvt_pk_bf16(sc[c >> 1][b0 + 0], sc[c >> 1][b0 + 1]);
        int wb = cvt_pk_bf16(sc[c >> 1][b0 + 4], sc[c >> 1][b0 + 5]);
        asm volatile("v_permlane32_swap_b32 %0, %1" : "+v"(wa), "+v"(wb));
        int wc2 = cvt_pk_bf16(sc[c >> 1][b0 + 2], sc[c >> 1][b0 + 3]);
        int wd = cvt_pk_bf16(sc[c >> 1][b0 + 6], sc[c >> 1][b0 + 7]);
        asm volatile("v_permlane32_swap_b32 %0, %1" : "+v"(wc2), "+v"(wd));
        int4 pw;
        pw.x = wa; pw.y = wc2; pw.z = wb; pw.w = wd;
        pa[qb][c] = __builtin_bit_cast(bf16x8, pw);
      }
    }

    // PV as O^T = mfma(V^T, P^T): each vf read feeds both q-blocks
    __builtin_amdgcn_s_setprio(1);
#pragma unroll
    for (int df = 0; df < 2; df++) {
#pragma unroll
      for (int c = 0; c < 4; c++) {
        int row = df * 32 + q31;
        bf16x8 vf = *reinterpret_cast<const bf16x8*>(VB + row * 128 + ((c * 32 + h * 16) ^ swz));
        oacc[0][df] = __builtin_amdgcn_mfma_f32_32x32x16_bf16(vf, pa[0][c], oacc[0][df], 0, 0, 0);
        oacc[1][df] = __builtin_amdgcn_mfma_f32_32x32x16_bf16(vf, pa[1][c], oacc[1][df], 0, 0, 0);
      }
    }
    __builtin_amdgcn_s_setprio(0);
  }

  // epilogue: O^T row d = df*32 + 8*rq + (r&3) + 4h, col q = lane&31
#pragma unroll
  for (int qb = 0; qb < 2; qb++) {
    float inv = 1.0f / l_run[qb];
    short* aob = AO + (size_t)(q0 + qb * 32 + q31) * HID + head * HD;
#pragma unroll
    for (int df = 0; df < 2; df++) {
#pragma unroll
      for (int rq = 0; rq < 4; rq++) {
        int v0 = cvt_pk_bf16(oacc[qb][df][rq * 4 + 0] * inv, oacc[qb][df][rq * 4 + 1] * inv);
        int v1 = cvt_pk_bf16(oacc[qb][df][rq * 4 + 2] * inv, oacc[qb][df][rq * 4 + 3] * inv);
        int2 st;
        st.x = v0; st.y = v1;
        *reinterpret_cast<int2*>(aob + df * 32 + rq * 8 + h * 4) = st;
      }
    }
  }
}

// ---------------- launch ----------------
extern "C" void kernel_launch(void* const* d_in, const int* in_sizes, int n_in,
                              void* d_out, int out_size, void* d_ws, size_t ws_size,
                              hipStream_t stream) {
  const float* x  = (const float*)d_in[0];
  const float* Wq = (const float*)d_in[1];
  const float* bq = (const float*)d_in[2];
  const float* Wk = (const float*)d_in[3];
  const float* bk = (const float*)d_in[4];
  const float* Wv = (const float*)d_in[5];
  const float* bv = (const float*)d_in[6];
  const float* Wo = (const float*)d_in[7];
  const float* bo = (const float*)d_in[8];
  const float* qg = (const float*)d_in[9];
  const float* qb = (const float*)d_in[10];
  const float* kg = (const float*)d_in[11];
  const float* kb2 = (const float*)d_in[12];
  float* out = (float*)d_out;

  char* ws = (char*)d_ws;
  size_t off = 0;
  auto alloc = [&](size_t bytes) {
    void* p = ws + off;
    off += (bytes + 255) & ~(size_t)255;
    return p;
  };
  short* xb    = (short*)alloc((size_t)2048 * 2048 * 2);
  short* Wqkvt = (short*)alloc((size_t)3072 * 2048 * 2);
  short* Wot   = (short*)alloc((size_t)2048 * 2048 * 2);
  short* QKVp  = (short*)alloc((size_t)2048 * 3072 * 2);
  short* Qr    = (short*)alloc((size_t)NH * 2048 * 64 * 2);
  short* Kr    = (short*)alloc((size_t)NKV * 2048 * 64 * 2);
  short* Vt    = (short*)alloc((size_t)NKV * 64 * 2048 * 2);
  short* AO    = (short*)alloc((size_t)2048 * 2048 * 2);
  float* ctab  = (float*)alloc((size_t)2048 * 32 * 4);
  float* stab  = (float*)alloc((size_t)2048 * 32 * 4);
  float* bqkv  = (float*)alloc((size_t)3072 * 4);

  cast_bf16_kernel<<<(2048 * 2048 / 4 + 255) / 256, 256, 0, stream>>>(x, xb, 2048 * 2048 / 4);
  transpose_cast_kernel<<<dim3(32, 32), 256, 0, stream>>>(Wq, Wqkvt, 2048, 2048);
  transpose_cast_kernel<<<dim3(32, 8), 256, 0, stream>>>(Wk, Wqkvt + (size_t)2048 * 2048, 2048, 512);
  transpose_cast_kernel<<<dim3(32, 8), 256, 0, stream>>>(Wv, Wqkvt + (size_t)2560 * 2048, 2048, 512);
  transpose_cast_kernel<<<dim3(32, 32), 256, 0, stream>>>(Wo, Wot, 2048, 2048);
  concat_bias_kernel<<<12, 256, 0, stream>>>(bq, bk, bv, bqkv);
  rope_table_kernel<<<256, 256, 0, stream>>>(ctab, stab);

  // QKV: M=2048 (Mt=32), N=3072 -> grid 32*24 = 768 blocks
  gemm_v2_kernel<0><<<768, 256, 0, stream>>>(xb, Wqkvt, bqkv, QKVp, 3072, 2048);

  // Q pre-scale = 1/sqrt(64) * log2(e)  (softmax runs in exp2 domain)
  ln_rope_kernel<<<512, 256, 0, stream>>>(QKVp, 3072, 5, qg, qb, ctab, stab, 0.125f * 1.44269504089f, Qr);
  ln_rope_kernel<<<256, 256, 0, stream>>>(QKVp + 2048, 3072, 3, kg, kb2, ctab, stab, 1.0f, Kr);
  v_transpose_kernel<<<dim3(8, 32), 256, 0, stream>>>(QKVp + 2560, Vt);

  // 256 blocks x 256 thr; ~2 blocks/CU; XCD-grouped KV
  attn_kernel<<<256, 256, 0, stream>>>(Qr, Kr, Vt, AO);

  // Out-proj: M=2048, N=2048 -> grid 32*16 = 512 blocks
  gemm_v2_kernel<1><<<512, 256, 0, stream>>>(AO, Wot, bo, out, 2048, 2048);
}

// Round 9
// 329.807 us; speedup vs baseline: 1.0449x; 1.0449x over previous
//
#include <hip/hip_runtime.h>
#include <hip/hip_bf16.h>
#include <stdint.h>

#define S_LEN 2048
#define HID   2048
#define NH    32
#define NKV   8
#define HD    64

typedef __attribute__((ext_vector_type(8))) short bf16x8;
typedef __attribute__((ext_vector_type(4))) float f32x4;
typedef __attribute__((ext_vector_type(16))) float f32x16;

__device__ __forceinline__ short f2bf(float f) {
  __hip_bfloat16 h = __float2bfloat16(f);
  return __builtin_bit_cast(short, h);
}
__device__ __forceinline__ float bf2f(short s) {
  unsigned u = ((unsigned)(unsigned short)s) << 16;
  return __builtin_bit_cast(float, u);
}
__device__ __forceinline__ int cvt_pk_bf16(float lo, float hi) {
  int r;
  asm("v_cvt_pk_bf16_f32 %0, %1, %2" : "=v"(r) : "v"(lo), "v"(hi));
  return r;
}

// ---------------- cast fp32 -> bf16 ----------------
__global__ void cast_bf16_kernel(const float* __restrict__ in, short* __restrict__ out, int n4) {
  int i = blockIdx.x * blockDim.x + threadIdx.x;
  if (i < n4) {
    float4 v = reinterpret_cast<const float4*>(in)[i];
    short4 o;
    o.x = f2bf(v.x); o.y = f2bf(v.y); o.z = f2bf(v.z); o.w = f2bf(v.w);
    reinterpret_cast<short4*>(out)[i] = o;
  }
}

// ---------------- transpose + cast: in [K][N] f32 -> out [N][K] bf16 ----------------
__global__ void transpose_cast_kernel(const float* __restrict__ in, short* __restrict__ out,
                                      int K, int N) {
  __shared__ float tile[64][65];
  const int k0 = blockIdx.x * 64;
  const int n0 = blockIdx.y * 64;
  const int tn = threadIdx.x & 63;
  const int t4 = threadIdx.x >> 6;
#pragma unroll
  for (int i = 0; i < 16; i++)
    tile[t4 + i * 4][tn] = in[(size_t)(k0 + t4 + i * 4) * N + n0 + tn];
  __syncthreads();
#pragma unroll
  for (int i = 0; i < 16; i++)
    out[(size_t)(n0 + t4 + i * 4) * K + k0 + tn] = f2bf(tile[tn][t4 + i * 4]);
}

// ---------------- concat bias [2048|512|512] ----------------
__global__ void concat_bias_kernel(const float* __restrict__ bq, const float* __restrict__ bk,
                                   const float* __restrict__ bv, float* __restrict__ out) {
  int i = blockIdx.x * blockDim.x + threadIdx.x;
  if (i < 3072) {
    float v = (i < 2048) ? bq[i] : (i < 2560 ? bk[i - 2048] : bv[i - 2560]);
    out[i] = v;
  }
}

// ---------------- RoPE tables: [S][32] cos and sin ----------------
__global__ void rope_table_kernel(float* __restrict__ ctab, float* __restrict__ stab) {
  int i = blockIdx.x * blockDim.x + threadIdx.x;
  if (i < S_LEN * 32) {
    int t = i >> 5, j = i & 31;
    float ang = (float)t * powf(10000.0f, -(float)j / 32.0f);
    ctab[i] = cosf(ang);
    stab[i] = sinf(ang);
  }
}

// ---------------- GEMM v2: C[M][N] = A[M][K] * Bt[N][K]^T + bias ----------------
template <int F32OUT>
__global__ __launch_bounds__(256, 3) void gemm_v2_kernel(
    const short* __restrict__ A, const short* __restrict__ Bt,
    const float* __restrict__ bias, void* __restrict__ Cv,
    int N, int K) {
  __shared__ short Als[2][64 * 64];
  __shared__ short Bls[2][128 * 64];
  const int tid = threadIdx.x;
  const int l = tid & 63, w = tid >> 6;
  const int lg = l >> 4, lc = l & 15;
  const int wr = w >> 1, wc = w & 1;

  const int nwg = gridDim.x;
  const int cpx = nwg >> 3;
  const int swz = (blockIdx.x & 7) * cpx + (blockIdx.x >> 3);
  const int m0 = (swz & 31) << 6;
  const int n0 = (swz >> 5) << 7;

  const int NT = K >> 6;
  const f32x4 zero4 = {0.f, 0.f, 0.f, 0.f};
  f32x4 acc[2][4];
#pragma unroll
  for (int i = 0; i < 2; i++)
#pragma unroll
    for (int j = 0; j < 4; j++) acc[i][j] = zero4;

  const int lrow = l >> 3;
  const int lcol = (l & 7) << 3;

  auto stage = [&](int buf, int kt) {
    const int kofs = kt << 6;
#pragma unroll
    for (int i = 0; i < 2; i++) {
      const short* gsrc = A + (size_t)(m0 + i * 32 + (w << 3) + lrow) * K + kofs + lcol;
      __builtin_amdgcn_global_load_lds(
          (const __attribute__((address_space(1))) unsigned*)gsrc,
          (__attribute__((address_space(3))) unsigned*)(&Als[buf][(i * 32 + (w << 3)) << 6]),
          16, 0, 0);
    }
#pragma unroll
    for (int i = 0; i < 4; i++) {
      const short* gsrc = Bt + (size_t)(n0 + i * 32 + (w << 3) + lrow) * K + kofs + lcol;
      __builtin_amdgcn_global_load_lds(
          (const __attribute__((address_space(1))) unsigned*)gsrc,
          (__attribute__((address_space(3))) unsigned*)(&Bls[buf][(i * 32 + (w << 3)) << 6]),
          16, 0, 0);
    }
  };

  stage(0, 0);
  int cur = 0;
  for (int kt = 0; kt < NT; kt++) {
    __syncthreads();
    if (kt + 1 < NT) stage(cur ^ 1, kt + 1);
    const char* AB = reinterpret_cast<const char*>(Als[cur]);
    const char* BB = reinterpret_cast<const char*>(Bls[cur]);
#pragma unroll
    for (int ks = 0; ks < 2; ks++) {
      bf16x8 af[2], bfr[4];
#pragma unroll
      for (int mi = 0; mi < 2; mi++)
        af[mi] = *reinterpret_cast<const bf16x8*>(
            AB + (wr * 32 + mi * 16 + lc) * 128 + ks * 64 + lg * 16);
#pragma unroll
      for (int nf = 0; nf < 4; nf++)
        bfr[nf] = *reinterpret_cast<const bf16x8*>(
            BB + (wc * 64 + nf * 16 + lc) * 128 + ks * 64 + lg * 16);
#pragma unroll
      for (int mi = 0; mi < 2; mi++)
#pragma unroll
        for (int nf = 0; nf < 4; nf++)
          acc[mi][nf] = __builtin_amdgcn_mfma_f32_16x16x32_bf16(af[mi], bfr[nf], acc[mi][nf], 0, 0, 0);
    }
    cur ^= 1;
  }

#pragma unroll
  for (int mi = 0; mi < 2; mi++) {
#pragma unroll
    for (int nf = 0; nf < 4; nf++) {
      int col = n0 + wc * 64 + nf * 16 + lc;
      float bv = bias[col];
#pragma unroll
      for (int r = 0; r < 4; r++) {
        int rowg = m0 + wr * 32 + mi * 16 + lg * 4 + r;
        float v = acc[mi][nf][r] + bv;
        if (F32OUT)
          reinterpret_cast<float*>(Cv)[(size_t)rowg * N + col] = v;
        else
          reinterpret_cast<short*>(Cv)[(size_t)rowg * N + col] = f2bf(v);
      }
    }
  }
}

// ---------------- fused per-head LayerNorm + RoPE ----------------
__global__ void ln_rope_kernel(const short* __restrict__ In, int instride, int nh_shift,
                               const float* __restrict__ gam, const float* __restrict__ bet,
                               const float* __restrict__ ctab, const float* __restrict__ stab,
                               float scale, short* __restrict__ Out) {
  const int lane = threadIdx.x & 63;
  const int nh = 1 << nh_shift;
  const int nrows = S_LEN << nh_shift;
  int row = (blockIdx.x * blockDim.x + threadIdx.x) >> 6;
  const int step = (gridDim.x * blockDim.x) >> 6;
  const float g = gam[lane], b = bet[lane];
  for (; row < nrows; row += step) {
    const int t = row >> nh_shift;
    const int h = row & (nh - 1);
    float x = bf2f(In[(size_t)t * instride + h * HD + lane]);
    float s = x;
#pragma unroll
    for (int m = 32; m >= 1; m >>= 1) s += __shfl_xor(s, m);
    const float mu = s * (1.0f / 64.0f);
    float d = x - mu;
    float v2 = d * d;
#pragma unroll
    for (int m = 32; m >= 1; m >>= 1) v2 += __shfl_xor(v2, m);
    const float var = v2 * (1.0f / 64.0f);
    float y = d * rsqrtf(var + 1e-5f) * g + b;
    float part = __shfl_xor(y, 32);
    const float c = ctab[t * 32 + (lane & 31)];
    const float sn = stab[t * 32 + (lane & 31)];
    float o = (lane < 32) ? (y * c - part * sn) : (y * c + part * sn);
    Out[((size_t)h * S_LEN + t) * HD + lane] = f2bf(o * scale);
  }
}

// ---------------- V transpose via LDS: [t][3072 stride] -> [g][d][t] ----------------
__global__ void v_transpose_kernel(const short* __restrict__ In, short* __restrict__ Vt) {
  __shared__ short tile[64][66];
  const int g = blockIdx.x;
  const int t0 = blockIdx.y * 64;
  const int lane = threadIdx.x & 63, w = threadIdx.x >> 6;
#pragma unroll
  for (int i = 0; i < 16; i++) {
    int r = i * 4 + w;
    tile[r][lane] = In[(size_t)(t0 + r) * 3072 + g * 64 + lane];
  }
  __syncthreads();
#pragma unroll
  for (int i = 0; i < 16; i++) {
    int d = i * 4 + w;
    Vt[((size_t)g * 64 + d) * 2048 + t0 + lane] = tile[lane][d];
  }
}

// ---------------- flash attention v4: qq=2, fixed-max softmax, 2-way SPLIT-KV ----------------
// Grid 512: sp = bid>>8 selects KV half [16sp,16sp+16); low 8 bits decode as before.
// Each split writes UNNORMALIZED partial O (bf16) + partial l; fixed-max softmax means
// partials combine by simple addition (no max renorm). 2 blocks/CU -> 8 waves/CU.
__global__ __launch_bounds__(256, 2) void attn_kernel(
    const short* __restrict__ Q, const short* __restrict__ Kk,
    const short* __restrict__ Vt, short* __restrict__ Op0,
    short* __restrict__ Op1, float* __restrict__ lpart) {
  __shared__ short Kls[64 * 64];
  __shared__ short Vls[64 * 64];
  const int tid = threadIdx.x;
  const int l = tid & 63;
  const int w = tid >> 6;          // warp 0..3
  const int q31 = l & 31;
  const int h = l >> 5;            // lane half

  const int bid = blockIdx.x;
  const int sp = bid >> 8;                    // KV split 0/1
  const int id8 = bid & 255;
  // XCD-aware decode: all 32 low-id blocks on one XCD share one KV group.
  const int v = (id8 & 7) * 32 + (id8 >> 3);
  const int g = v >> 5;                       // kv group 0..7
  const int within = v & 31;
  const int head = (g << 2) + (within >> 3);  // 4 heads per group
  const int q0 = (within & 7) * 256 + w * 64; // warp covers q0..q0+63

  short* __restrict__ Op = sp ? Op1 : Op0;
  float* __restrict__ lp = lpart + sp * (NH * S_LEN);

  // Q B-frags for both q-blocks
  bf16x8 qf[2][4];
#pragma unroll
  for (int qb = 0; qb < 2; qb++) {
    const short* qbp = Q + ((size_t)head * S_LEN + q0 + qb * 32 + q31) * HD;
#pragma unroll
    for (int ks = 0; ks < 4; ks++)
      qf[qb][ks] = *reinterpret_cast<const bf16x8*>(qbp + ks * 16 + h * 8);
  }

  f32x16 oacc[2][2];
#pragma unroll
  for (int qb = 0; qb < 2; qb++)
#pragma unroll
    for (int df = 0; df < 2; df++)
#pragma unroll
      for (int r = 0; r < 16; r++) oacc[qb][df][r] = 0.f;
  float l_run[2] = {0.f, 0.f};

  // staging: 256 threads, 2 passes per tensor (64 rows x 128B)
  const int srow = tid >> 3;           // 0..31
  const int kb = (tid & 7) << 4;
  const int kbs = kb ^ ((srow & 7) << 4);
  int4 kr[2], vr[2];
  auto stage_load = [&](int kt) {
#pragma unroll
    for (int c = 0; c < 2; c++) {
      int row = c * 32 + srow;
      kr[c] = *reinterpret_cast<const int4*>(Kk + ((size_t)g * S_LEN + kt * 64 + row) * HD + (kb >> 1));
      vr[c] = *reinterpret_cast<const int4*>(Vt + ((size_t)g * HD + row) * S_LEN + kt * 64 + (kb >> 1));
    }
  };

  const int kt0 = sp << 4, kt1 = kt0 + 16;
  stage_load(kt0);

  const int swz = (l & 7) << 4;
  const char* KB = reinterpret_cast<const char*>(Kls);
  const char* VB = reinterpret_cast<const char*>(Vls);

  for (int kt = kt0; kt < kt1; kt++) {
    __syncthreads();  // prev tile LDS reads done
#pragma unroll
    for (int c = 0; c < 2; c++) {
      int row = c * 32 + srow;
      *reinterpret_cast<int4*>(reinterpret_cast<char*>(Kls) + row * 128 + kbs) = kr[c];
      *reinterpret_cast<int4*>(reinterpret_cast<char*>(Vls) + row * 128 + kbs) = vr[c];
    }
    if (kt + 1 < kt1) stage_load(kt + 1);
    __syncthreads();  // staged

    // QK^T swapped, both q-blocks share each kf read: C[k][q], q = lane&31
    f32x16 sc0[2], sc1[2];
#pragma unroll
    for (int i = 0; i < 16; i++) { sc0[0][i] = 0.f; sc0[1][i] = 0.f; sc1[0][i] = 0.f; sc1[1][i] = 0.f; }
    __builtin_amdgcn_s_setprio(1);
#pragma unroll
    for (int ks = 0; ks < 4; ks++) {
#pragma unroll
      for (int kc = 0; kc < 2; kc++) {
        int row = kc * 32 + q31;
        bf16x8 kf = *reinterpret_cast<const bf16x8*>(KB + row * 128 + ((ks * 32 + h * 16) ^ swz));
        sc0[kc] = __builtin_amdgcn_mfma_f32_32x32x16_bf16(kf, qf[0][ks], sc0[kc], 0, 0, 0);
        sc1[kc] = __builtin_amdgcn_mfma_f32_32x32x16_bf16(kf, qf[1][ks], sc1[kc], 0, 0, 0);
      }
    }
    __builtin_amdgcn_s_setprio(0);

    // fixed-max softmax (log2 domain): p = exp2(s - 12); |s*log2e| <= 11.54 by
    // Cauchy-Schwarz on LN-normalized rows -> exact softmax with constant max.
    bf16x8 pa[2][4];
#pragma unroll
    for (int qb = 0; qb < 2; qb++) {
      f32x16* sc = (qb == 0) ? sc0 : sc1;
      float ps = 0.f;
#pragma unroll
      for (int kc = 0; kc < 2; kc++)
#pragma unroll
        for (int r = 0; r < 16; r++) {
          float p = __builtin_exp2f(sc[kc][r] - 12.0f);
          sc[kc][r] = p;
          ps += p;
        }
      ps += __shfl_xor(ps, 32);             // cross-half sum
      l_run[qb] += ps;

      // P(f32, C-layout) -> bf16 A/B-frags via cvt_pk + permlane32_swap (T12)
#pragma unroll
      for (int c = 0; c < 4; c++) {
        const int b0 = (c & 1) * 8;
        int wa = cvt_pk_bf16(sc[c >> 1][b0 + 0], sc[c >> 1][b0 + 1]);
        int wb = cvt_pk_bf16(sc[c >> 1][b0 + 4], sc[c >> 1][b0 + 5]);
        asm volatile("v_permlane32_swap_b32 %0, %1" : "+v"(wa), "+v"(wb));
        int wc2 = cvt_pk_bf16(sc[c >> 1][b0 + 2], sc[c >> 1][b0 + 3]);
        int wd = cvt_pk_bf16(sc[c >> 1][b0 + 6], sc[c >> 1][b0 + 7]);
        asm volatile("v_permlane32_swap_b32 %0, %1" : "+v"(wc2), "+v"(wd));
        int4 pw;
        pw.x = wa; pw.y = wc2; pw.z = wb; pw.w = wd;
        pa[qb][c] = __builtin_bit_cast(bf16x8, pw);
      }
    }

    // PV as O^T = mfma(V^T, P^T): each vf read feeds both q-blocks
    __builtin_amdgcn_s_setprio(1);
#pragma unroll
    for (int df = 0; df < 2; df++) {
#pragma unroll
      for (int c = 0; c < 4; c++) {
        int row = df * 32 + q31;
        bf16x8 vf = *reinterpret_cast<const bf16x8*>(VB + row * 128 + ((c * 32 + h * 16) ^ swz));
        oacc[0][df] = __builtin_amdgcn_mfma_f32_32x32x16_bf16(vf, pa[0][c], oacc[0][df], 0, 0, 0);
        oacc[1][df] = __builtin_amdgcn_mfma_f32_32x32x16_bf16(vf, pa[1][c], oacc[1][df], 0, 0, 0);
      }
    }
    __builtin_amdgcn_s_setprio(0);
  }

  // epilogue: UNNORMALIZED partial O (bf16) + l. O^T row d = df*32+rq*8+(r&3)+4h, col q=lane&31.
#pragma unroll
  for (int qb = 0; qb < 2; qb++) {
    const int q = q0 + qb * 32 + q31;
    if (h == 0) lp[head * S_LEN + q] = l_run[qb];
    short* ob = Op + (size_t)q * HID + head * HD;
#pragma unroll
    for (int df = 0; df < 2; df++) {
#pragma unroll
      for (int rq = 0; rq < 4; rq++) {
        int v0 = cvt_pk_bf16(oacc[qb][df][rq * 4 + 0], oacc[qb][df][rq * 4 + 1]);
        int v1 = cvt_pk_bf16(oacc[qb][df][rq * 4 + 2], oacc[qb][df][rq * 4 + 3]);
        int2 st;
        st.x = v0; st.y = v1;
        *reinterpret_cast<int2*>(ob + df * 32 + rq * 8 + h * 4) = st;
      }
    }
  }
}

// ---------------- combine partials: AO = (Op0 + Op1) / (l0 + l1) ----------------
__global__ void combine_kernel(const short* __restrict__ Op0, const short* __restrict__ Op1,
                               const float* __restrict__ lpart, short* __restrict__ AO) {
  int i = blockIdx.x * blockDim.x + threadIdx.x;  // 4-elem groups: 2048*512
  int t = i >> 9;
  int c = i & 511;
  int h = c >> 4;
  float inv = 1.0f / (lpart[h * S_LEN + t] + lpart[NH * S_LEN + h * S_LEN + t]);
  short4 a = reinterpret_cast<const short4*>(Op0)[i];
  short4 b = reinterpret_cast<const short4*>(Op1)[i];
  int v0 = cvt_pk_bf16((bf2f(a.x) + bf2f(b.x)) * inv, (bf2f(a.y) + bf2f(b.y)) * inv);
  int v1 = cvt_pk_bf16((bf2f(a.z) + bf2f(b.z)) * inv, (bf2f(a.w) + bf2f(b.w)) * inv);
  int2 st;
  st.x = v0; st.y = v1;
  reinterpret_cast<int2*>(AO)[i] = st;
}

// ---------------- launch ----------------
extern "C" void kernel_launch(void* const* d_in, const int* in_sizes, int n_in,
                              void* d_out, int out_size, void* d_ws, size_t ws_size,
                              hipStream_t stream) {
  const float* x  = (const float*)d_in[0];
  const float* Wq = (const float*)d_in[1];
  const float* bq = (const float*)d_in[2];
  const float* Wk = (const float*)d_in[3];
  const float* bk = (const float*)d_in[4];
  const float* Wv = (const float*)d_in[5];
  const float* bv = (const float*)d_in[6];
  const float* Wo = (const float*)d_in[7];
  const float* bo = (const float*)d_in[8];
  const float* qg = (const float*)d_in[9];
  const float* qb = (const float*)d_in[10];
  const float* kg = (const float*)d_in[11];
  const float* kb2 = (const float*)d_in[12];
  float* out = (float*)d_out;

  char* ws = (char*)d_ws;
  size_t off = 0;
  auto alloc = [&](size_t bytes) {
    void* p = ws + off;
    off += (bytes + 255) & ~(size_t)255;
    return p;
  };
  short* xb    = (short*)alloc((size_t)2048 * 2048 * 2);
  short* Wqkvt = (short*)alloc((size_t)3072 * 2048 * 2);
  short* Wot   = (short*)alloc((size_t)2048 * 2048 * 2);
  short* QKVp  = (short*)alloc((size_t)2048 * 3072 * 2);
  short* Qr    = (short*)alloc((size_t)NH * 2048 * 64 * 2);
  short* Kr    = (short*)alloc((size_t)NKV * 2048 * 64 * 2);
  short* Vt    = (short*)alloc((size_t)NKV * 64 * 2048 * 2);
  short* AO    = (short*)alloc((size_t)2048 * 2048 * 2);
  float* ctab  = (float*)alloc((size_t)2048 * 32 * 4);
  float* stab  = (float*)alloc((size_t)2048 * 32 * 4);
  float* bqkv  = (float*)alloc((size_t)3072 * 4);
  float* lpart = (float*)alloc((size_t)2 * NH * 2048 * 4);
  // Partial-O buffers ALIAS dead regions: xb is dead after the QKV GEMM,
  // QKVp is dead after ln_rope / v_transpose. Both are exactly [2048][2048] bf16-sized.
  short* Op0 = QKVp;   // 8.39 MB needed, 12.6 MB region
  short* Op1 = xb;     // 8.39 MB needed, 8.39 MB region

  cast_bf16_kernel<<<(2048 * 2048 / 4 + 255) / 256, 256, 0, stream>>>(x, xb, 2048 * 2048 / 4);
  transpose_cast_kernel<<<dim3(32, 32), 256, 0, stream>>>(Wq, Wqkvt, 2048, 2048);
  transpose_cast_kernel<<<dim3(32, 8), 256, 0, stream>>>(Wk, Wqkvt + (size_t)2048 * 2048, 2048, 512);
  transpose_cast_kernel<<<dim3(32, 8), 256, 0, stream>>>(Wv, Wqkvt + (size_t)2560 * 2048, 2048, 512);
  transpose_cast_kernel<<<dim3(32, 32), 256, 0, stream>>>(Wo, Wot, 2048, 2048);
  concat_bias_kernel<<<12, 256, 0, stream>>>(bq, bk, bv, bqkv);
  rope_table_kernel<<<256, 256, 0, stream>>>(ctab, stab);

  // QKV: M=2048 (Mt=32), N=3072 -> grid 32*24 = 768 blocks
  gemm_v2_kernel<0><<<768, 256, 0, stream>>>(xb, Wqkvt, bqkv, QKVp, 3072, 2048);

  // Q pre-scale = 1/sqrt(64) * log2(e)  (softmax runs in exp2 domain)
  ln_rope_kernel<<<512, 256, 0, stream>>>(QKVp, 3072, 5, qg, qb, ctab, stab, 0.125f * 1.44269504089f, Qr);
  ln_rope_kernel<<<256, 256, 0, stream>>>(QKVp + 2048, 3072, 3, kg, kb2, ctab, stab, 1.0f, Kr);
  v_transpose_kernel<<<dim3(8, 32), 256, 0, stream>>>(QKVp + 2560, Vt);

  // 512 blocks (2-way KV split) = 2 blocks/CU = 8 waves/CU
  attn_kernel<<<512, 256, 0, stream>>>(Qr, Kr, Vt, Op0, Op1, lpart);
  combine_kernel<<<4096, 256, 0, stream>>>(Op0, Op1, lpart, AO);

  // Out-proj: M=2048, N=2048 -> grid 32*16 = 512 blocks
  gemm_v2_kernel<1><<<512, 256, 0, stream>>>(AO, Wot, bo, out, 2048, 2048);
}